// Round 5
// baseline (786.324 us; speedup 1.0000x reference)
//
#include <hip/hip_runtime.h>
#include <hip/hip_bf16.h>
#include <math.h>

typedef unsigned long long ull;

#define EPS 1e-5

// ---------------------------------------------------------------------------
// Ballot-based conv weight packing. One block per co; stage the co's
// (Cin,3,3) block into LDS coalesced, then each wave ballots one word.
// Output layout [tap][kc][co], bit b <-> ci = kc*64+b, bit = (w > 0).
// ---------------------------------------------------------------------------
__global__ __launch_bounds__(256) void pack_conv_w(const float* __restrict__ w,
                                                   ull* __restrict__ out,
                                                   int Cout, int Cin) {
    extern __shared__ float lw[];       // Cin*9 floats
    int co = blockIdx.x;
    int n = Cin * 9;
    const float* base = w + (size_t)co * n;
    for (int i = threadIdx.x; i < n; i += 256) lw[i] = base[i];
    __syncthreads();
    int KC = Cin >> 6;
    int lane = threadIdx.x & 63;
    int wv = threadIdx.x >> 6;
    for (int widx = wv; widx < 9 * KC; widx += 4) {
        int tap = widx / KC, kc = widx % KC;
        float f = lw[(kc * 64 + lane) * 9 + tap];   // stride 9 -> conflict-free
        ull bits = __ballot(f > 0.f);
        if (lane == 0) out[((size_t)tap * KC + kc) * Cout + co] = bits;
    }
}

// lw1 (1024, 8192): word wi = s*8+kc (s=y*4+x), bit b <-> c = kc*64+b,
// flat k = c*16 + s. Stored [wi][co]. Staged padded (+1 per 16) in LDS.
__global__ __launch_bounds__(256) void pack_lw1(const float* __restrict__ w,
                                                ull* __restrict__ out) {
    __shared__ float lw[512 * 17];
    int co = blockIdx.x;
    const float* base = w + (size_t)co * 8192;
    for (int k = threadIdx.x; k < 8192; k += 256)
        lw[(k >> 4) * 17 + (k & 15)] = base[k];
    __syncthreads();
    int lane = threadIdx.x & 63;
    int wv = threadIdx.x >> 6;
    for (int wi = wv; wi < 128; wi += 4) {
        int s = wi >> 3, kc = wi & 7;
        float f = lw[(kc * 64 + lane) * 17 + s];
        ull bits = __ballot(f > 0.f);
        if (lane == 0) out[(size_t)wi * 1024 + co] = bits;
    }
}

// lw2 (1024x1024) / lw3 (10x1024): stored [wi][rows], bit b <-> k = wi*64+b
__global__ __launch_bounds__(256) void pack_lw_lin(const float* __restrict__ w,
                                                   ull* __restrict__ out,
                                                   int rows) {
    __shared__ float lw[1024];
    int co = blockIdx.x;
    const float* base = w + (size_t)co * 1024;
    for (int k = threadIdx.x; k < 1024; k += 256) lw[k] = base[k];
    __syncthreads();
    int lane = threadIdx.x & 63;
    int wv = threadIdx.x >> 6;
    for (int wi = wv; wi < 16; wi += 4) {
        float f = lw[wi * 64 + lane];
        ull bits = __ballot(f > 0.f);
        if (lane == 0) out[(size_t)wi * rows + co] = bits;
    }
}

// ---------------------------------------------------------------------------
// Conv1: real input x (32,3,32,32), binarized weights (384,3,3,3), fp64 acc.
// One block per (n, row): x window staged in LDS, 384 threads = one co each.
// ---------------------------------------------------------------------------
__global__ __launch_bounds__(384) void conv1_bn_sign(
    const float* __restrict__ x, const float* __restrict__ cw,
    const float* __restrict__ cb, const float* __restrict__ g,
    const float* __restrict__ bb, const float* __restrict__ m,
    const float* __restrict__ v, ull* __restrict__ out) {
    __shared__ double xs[3][3][34];
    int blk = blockIdx.x;             // n*32 + y
    int y = blk & 31, n = blk >> 5;
    for (int i = threadIdx.x; i < 3 * 3 * 34; i += 384) {
        int col = i % 34;
        int r = i / 34;
        int ky = r % 3, ci = r / 3;
        int iy = y + ky - 1, ix = col - 1;
        double vv = 0.0;
        if ((unsigned)iy < 32u && (unsigned)ix < 32u)
            vv = (double)x[(((size_t)n * 3 + ci) * 32 + iy) * 32 + ix];
        xs[ci][ky][col] = vv;
    }
    __syncthreads();
    int co = threadIdx.x;
    double ws[27];
#pragma unroll
    for (int q = 0; q < 27; ++q) {
        float wv = cw[(size_t)co * 27 + q];
        ws[q] = (wv > 0.f) ? 1.0 : ((wv < 0.f) ? -1.0 : 0.0);
    }
    double inv = (double)g[co] / sqrt((double)v[co] + EPS);
    double addc = (double)cb[co] - (double)m[co];
    double bbv = (double)bb[co];
    ull* op = out + (size_t)blk * 32 * 6 + (co >> 6);
    for (int xx = 0; xx < 32; ++xx) {
        double acc = 0.0;
#pragma unroll
        for (int ci = 0; ci < 3; ++ci)
#pragma unroll
            for (int ky = 0; ky < 3; ++ky)
#pragma unroll
                for (int kx = 0; kx < 3; ++kx)
                    acc = fma(ws[(ci * 3 + ky) * 3 + kx], xs[ci][ky][xx + kx], acc);
        double tt = (acc + addc) * inv + bbv;
        ull mask = __ballot(tt > 0.0);
        if ((threadIdx.x & 63) == 0) op[(size_t)xx * 6] = mask;
    }
}

// ---------------------------------------------------------------------------
// Binary conv (+fused 2x2 maxpool) + bias + BN threshold + sign-pack.
// BRANCH-FREE core: the LDS window is ZERO-padded and the position nest runs
// with no bounds checks (pad words contribute popc(0^w)=popc(w)). Border
// blocks subtract the pad contribution in a uniform epilogue via per-tap
// weight popcounts (interior blocks skip that path entirely). Integer-exact;
// pool applied to raw integer dots. Natural [pp][KC] LDS layout (broadcast
// reads are conflict-free).
// ---------------------------------------------------------------------------
template <int KC, int KCC, int POOL, int PB, int BLK>
__global__ __launch_bounds__(BLK, 3) void binconv_kernel(
    const ull* __restrict__ act, const ull* __restrict__ wgt,
    const float* __restrict__ cb, const float* __restrict__ g,
    const float* __restrict__ bb, const float* __restrict__ m,
    const float* __restrict__ v, ull* __restrict__ out,
    int Hin, int Win, int Cout) {
    const int Hout = Hin / POOL, Wout = Win / POOL;
    constexpr int WH = POOL + 2, WW = PB * POOL + 2;
    constexpr int NPIX = PB * POOL * POOL;
    constexpr int NCH = KC / KCC;
    __shared__ __align__(16) ull lact[WH * WW * KC];
    int xb = blockIdx.x % (Wout / PB);
    int t = blockIdx.x / (Wout / PB);
    int yo = t % Hout;
    int n = t / Hout;
    int xo0 = xb * PB;
    int iy0 = yo * POOL - 1, ix0 = xo0 * POOL - 1;

    // ---- stage window, zero-padded ----
    for (int i = threadIdx.x; i < WH * WW * KC; i += BLK) {
        int pp = i / KC;
        int wy = pp / WW, wx = pp % WW;
        int iy = iy0 + wy, ix = ix0 + wx;
        ull val = 0;
        if ((unsigned)iy < (unsigned)Hin && (unsigned)ix < (unsigned)Win)
            val = act[(((size_t)n * Hin + iy) * Win + ix) * KC + (i % KC)];
        lact[i] = val;
    }
    __syncthreads();

    int co = blockIdx.y * BLK + (int)threadIdx.x;  // exact coverage

    int tot[NPIX];
#pragma unroll
    for (int i = 0; i < NPIX; ++i) tot[i] = 0;

    // ---- branch-free accumulation over ALL positions ----
#pragma unroll 1
    for (int ch = 0; ch < NCH; ++ch) {
        const int kc0 = ch * KCC;
        ull w[9][KCC];
#pragma unroll
        for (int tap = 0; tap < 9; ++tap)
#pragma unroll
            for (int i = 0; i < KCC; ++i)
                w[tap][i] = wgt[((size_t)tap * KC + kc0 + i) * Cout + co];

#pragma unroll
        for (int r = 0; r < WH; ++r)
#pragma unroll
            for (int c = 0; c < WW; ++c) {
                const ull* lp = lact + ((size_t)r * WW + c) * KC + kc0;
                ull a[KCC];
#pragma unroll
                for (int i = 0; i < KCC; ++i) a[i] = lp[i];
#pragma unroll
                for (int dy = (r >= 2 ? r - 2 : 0);
                     dy <= (r < POOL - 1 ? r : POOL - 1); ++dy) {
                    const int ky = r - dy;
#pragma unroll
                    for (int j = (c >= 2 ? c - 2 : 0);
                         j <= (c < PB * POOL - 1 ? c : PB * POOL - 1); ++j) {
                        const int kx = c - j;
                        const int tap = ky * 3 + kx;
                        const int pix =
                            (j / POOL) * (POOL * POOL) + dy * POOL + (j % POOL);
#pragma unroll
                        for (int i = 0; i < KCC; ++i)
                            tot[pix] += __popcll(a[i] ^ w[tap][i]);
                    }
                }
            }
    }

    // ---- uniform border correction: subtract pad-tap popc(w) ----
    if (iy0 < 0 || iy0 + WH > Hin || ix0 < 0 || ix0 + WW > Win) {
        int pw[9];
#pragma unroll
        for (int tap = 0; tap < 9; ++tap) {
            int s = 0;
#pragma unroll 1
            for (int kc = 0; kc < KC; ++kc)
                s += __popcll(wgt[((size_t)tap * KC + kc) * Cout + co]);
            pw[tap] = s;
        }
#pragma unroll
        for (int px = 0; px < PB; ++px)
#pragma unroll
            for (int dy = 0; dy < POOL; ++dy)
#pragma unroll
                for (int dx = 0; dx < POOL; ++dx) {
                    int py = yo * POOL + dy;
                    int pxa = (xo0 + px) * POOL + dx;
                    int pix = px * (POOL * POOL) + dy * POOL + dx;
#pragma unroll
                    for (int ky = 0; ky < 3; ++ky)
#pragma unroll
                        for (int kx = 0; kx < 3; ++kx) {
                            if ((unsigned)(py + ky - 1) >= (unsigned)Hin ||
                                (unsigned)(pxa + kx - 1) >= (unsigned)Win)
                                tot[pix] -= pw[ky * 3 + kx];
                        }
                }
    }

    double inv = (double)g[co] / sqrt((double)v[co] + EPS);
    double addc = (double)cb[co] - (double)m[co];
    double bbv = (double)bb[co];

    int KCOUT = Cout >> 6;
#pragma unroll
    for (int px = 0; px < PB; ++px) {
        int best = 0x80000000;
#pragma unroll
        for (int dy = 0; dy < POOL; ++dy)
#pragma unroll
            for (int dx = 0; dx < POOL; ++dx) {
                int py = yo * POOL + dy;
                int pxa = (xo0 + px) * POOL + dx;
                int cy = 3 - (py == 0) - (py == Hin - 1);
                int cx = 3 - (pxa == 0) - (pxa == Win - 1);
                int dot = cy * cx * (KC * 64) -
                          2 * tot[px * POOL * POOL + dy * POOL + dx];
                best = max(best, dot);
            }
        double tt = ((double)best + addc) * inv + bbv;
        ull mask = __ballot(tt > 0.0);
        if ((threadIdx.x & 63) == 0)
            out[(size_t)((n * Hout + yo) * Wout + xo0 + px) * KCOUT + (co >> 6)] =
                mask;
    }
}

// ---------------------------------------------------------------------------
// Binary FC + bias + BN threshold + sign-pack. Grid = (N, Cout/256).
// ---------------------------------------------------------------------------
template <int KCIN>
__global__ __launch_bounds__(256) void binfc_kernel(
    const ull* __restrict__ act, const ull* __restrict__ wgt,
    const float* __restrict__ lb, const float* __restrict__ g,
    const float* __restrict__ bb, const float* __restrict__ m,
    const float* __restrict__ v, ull* __restrict__ out, int Cout) {
    int n = blockIdx.x;
    int co = blockIdx.y * 256 + (int)threadIdx.x;
    const ull* ap = act + (size_t)n * KCIN;
    int mism = 0;
#pragma unroll 8
    for (int kc = 0; kc < KCIN; ++kc)
        mism += __popcll(ap[kc] ^ wgt[(size_t)kc * Cout + co]);
    int dot = 64 * KCIN - 2 * mism;
    double tt = ((double)dot + (double)lb[co] - (double)m[co]) *
                    ((double)g[co] / sqrt((double)v[co] + EPS)) +
                (double)bb[co];
    ull mask = __ballot(tt > 0.0);
    if (((int)threadIdx.x & 63) == 0)
        out[(size_t)n * (Cout >> 6) + ((unsigned)co >> 6)] = mask;
}

// ---------------------------------------------------------------------------
// Final FC3 (1024 -> 10) + affine-free BN + log_softmax, fp64. Grid = N.
// ---------------------------------------------------------------------------
__global__ __launch_bounds__(64) void fc3_softmax(
    const ull* __restrict__ act, const ull* __restrict__ wgt,
    const float* __restrict__ lb, const float* __restrict__ m9,
    const float* __restrict__ v9, float* __restrict__ out) {
    int n = blockIdx.x;
    __shared__ double z[10];
    int j = threadIdx.x;
    if (j < 10) {
        const ull* ap = act + (size_t)n * 16;
        int mism = 0;
#pragma unroll
        for (int kc = 0; kc < 16; ++kc) mism += __popcll(ap[kc] ^ wgt[kc * 10 + j]);
        int dot = 1024 - 2 * mism;
        z[j] = ((double)dot + (double)lb[j] - (double)m9[j]) /
               sqrt((double)v9[j] + EPS);
    }
    __syncthreads();
    if (j < 10) {
        double mx = z[0];
        for (int k = 1; k < 10; ++k) mx = fmax(mx, z[k]);
        double s = 0.0;
        for (int k = 0; k < 10; ++k) s += exp(z[k] - mx);
        out[n * 10 + j] = (float)(z[j] - mx - log(s));
    }
}

// ---------------------------------------------------------------------------
extern "C" void kernel_launch(void* const* d_in, const int* in_sizes, int n_in,
                              void* d_out, int out_size, void* d_ws, size_t ws_size,
                              hipStream_t stream) {
    (void)in_sizes; (void)n_in; (void)out_size; (void)ws_size;

    const float* x   = (const float*)d_in[0];
    const float* cw[6], *cbv[6];
    for (int i = 0; i < 6; ++i) {
        cw[i]  = (const float*)d_in[1 + 2 * i];
        cbv[i] = (const float*)d_in[2 + 2 * i];
    }
    const float *G[8], *B[8], *M[8], *V[8];
    for (int i = 0; i < 8; ++i) {
        G[i] = (const float*)d_in[13 + 4 * i];
        B[i] = (const float*)d_in[14 + 4 * i];
        M[i] = (const float*)d_in[15 + 4 * i];
        V[i] = (const float*)d_in[16 + 4 * i];
    }
    const float* m9  = (const float*)d_in[45];
    const float* v9  = (const float*)d_in[46];
    const float* lw1 = (const float*)d_in[47];
    const float* lb1 = (const float*)d_in[48];
    const float* lw2 = (const float*)d_in[49];
    const float* lb2 = (const float*)d_in[50];
    const float* lw3 = (const float*)d_in[51];
    const float* lb3 = (const float*)d_in[52];
    float* outp = (float*)d_out;

    ull* ws = (ull*)d_ws;
    // word offsets (8B units)
    ull* W2  = ws + 0;        // 20736
    ull* W3  = ws + 20736;    // 41472
    ull* W4  = ws + 62208;    // 82944
    ull* W5  = ws + 145152;   // 165888
    ull* W6  = ws + 311040;   // 110592
    ull* FW1 = ws + 421632;   // 131072
    ull* FW2 = ws + 552704;   // 16384
    ull* FW3 = ws + 569088;   // 160
    ull* A1  = ws + 569248;   // 196608 : 32x32x32 pixels x 6 words
    ull* A2  = ws + 765856;   // 49152  : 32x16x16 x 6
    ull* A3  = ws + 815008;   // 98304  : 32x16x16 x 12
    ull* A4  = ws + 913312;   // 24576  : 32x8x8 x 12
    ull* A5  = ws + 937888;   // 49152  : 32x8x8 x 24
    ull* A6  = ws + 987040;   // 4096   : 32x4x4 x 8
    ull* F1  = ws + 991136;   // 512    : 32 x 16
    ull* F2  = ws + 991648;   // 512    : 32 x 16

    // ---- pack weights (ballot-style, coalesced staging) ----
    pack_conv_w<<<384, 256, 384 * 9 * 4, stream>>>(cw[1], W2, 384, 384);
    pack_conv_w<<<768, 256, 384 * 9 * 4, stream>>>(cw[2], W3, 768, 384);
    pack_conv_w<<<768, 256, 768 * 9 * 4, stream>>>(cw[3], W4, 768, 768);
    pack_conv_w<<<1536, 256, 768 * 9 * 4, stream>>>(cw[4], W5, 1536, 768);
    pack_conv_w<<<512, 256, 1536 * 9 * 4, stream>>>(cw[5], W6, 512, 1536);
    pack_lw1<<<1024, 256, 0, stream>>>(lw1, FW1);
    pack_lw_lin<<<1024, 256, 0, stream>>>(lw2, FW2, 1024);
    pack_lw_lin<<<10, 256, 0, stream>>>(lw3, FW3, 10);

    // ---- layer 1: real conv, fp64, LDS-staged ----
    conv1_bn_sign<<<32 * 32, 384, 0, stream>>>(x, cw[0], cbv[0], G[0], B[0],
                                               M[0], V[0], A1);
    // ---- binary conv stack (branch-free, zero-padded windows) ----
    binconv_kernel<6, 3, 2, 4, 192><<<dim3(2048, 2), 192, 0, stream>>>(
        A1, W2, cbv[1], G[1], B[1], M[1], V[1], A2, 32, 32, 384);
    binconv_kernel<6, 3, 1, 8, 256><<<dim3(1024, 3), 256, 0, stream>>>(
        A2, W3, cbv[2], G[2], B[2], M[2], V[2], A3, 16, 16, 768);
    binconv_kernel<12, 3, 2, 4, 256><<<dim3(512, 3), 256, 0, stream>>>(
        A3, W4, cbv[3], G[3], B[3], M[3], V[3], A4, 16, 16, 768);
    binconv_kernel<12, 3, 1, 8, 256><<<dim3(256, 6), 256, 0, stream>>>(
        A4, W5, cbv[4], G[4], B[4], M[4], V[4], A5, 8, 8, 1536);
    binconv_kernel<24, 3, 2, 4, 256><<<dim3(128, 2), 256, 0, stream>>>(
        A5, W6, cbv[5], G[5], B[5], M[5], V[5], A6, 8, 8, 512);
    // ---- FC stack ----
    binfc_kernel<128><<<dim3(32, 4), 256, 0, stream>>>(A6, FW1, lb1, G[6], B[6],
                                                       M[6], V[6], F1, 1024);
    binfc_kernel<16><<<dim3(32, 4), 256, 0, stream>>>(F1, FW2, lb2, G[7], B[7],
                                                      M[7], V[7], F2, 1024);
    fc3_softmax<<<32, 64, 0, stream>>>(F2, FW3, lb3, m9, v9, outp);
}

// Round 6
// 699.222 us; speedup vs baseline: 1.1246x; 1.1246x over previous
//
#include <hip/hip_runtime.h>
#include <hip/hip_bf16.h>
#include <math.h>

typedef unsigned long long ull;

#define EPS 1e-5

// ---------------------------------------------------------------------------
// Ballot-based conv weight packing. One block per co; stage the co's
// (Cin,3,3) block into LDS coalesced, then each wave ballots one word.
// Output layout [tap][kc][co], bit b <-> ci = kc*64+b, bit = (w > 0).
// ---------------------------------------------------------------------------
__global__ __launch_bounds__(256) void pack_conv_w(const float* __restrict__ w,
                                                   ull* __restrict__ out,
                                                   int Cout, int Cin) {
    extern __shared__ float lw[];       // Cin*9 floats
    int co = blockIdx.x;
    int n = Cin * 9;
    const float* base = w + (size_t)co * n;
    for (int i = threadIdx.x; i < n; i += 256) lw[i] = base[i];
    __syncthreads();
    int KC = Cin >> 6;
    int lane = threadIdx.x & 63;
    int wv = threadIdx.x >> 6;
    for (int widx = wv; widx < 9 * KC; widx += 4) {
        int tap = widx / KC, kc = widx % KC;
        float f = lw[(kc * 64 + lane) * 9 + tap];   // stride 9 -> conflict-free
        ull bits = __ballot(f > 0.f);
        if (lane == 0) out[((size_t)tap * KC + kc) * Cout + co] = bits;
    }
}

// lw1 (1024, 8192): word wi = s*8+kc (s=y*4+x), bit b <-> c = kc*64+b,
// flat k = c*16 + s. Stored [wi][co]. Staged padded (+1 per 16) in LDS.
__global__ __launch_bounds__(256) void pack_lw1(const float* __restrict__ w,
                                                ull* __restrict__ out) {
    __shared__ float lw[512 * 17];
    int co = blockIdx.x;
    const float* base = w + (size_t)co * 8192;
    for (int k = threadIdx.x; k < 8192; k += 256)
        lw[(k >> 4) * 17 + (k & 15)] = base[k];
    __syncthreads();
    int lane = threadIdx.x & 63;
    int wv = threadIdx.x >> 6;
    for (int wi = wv; wi < 128; wi += 4) {
        int s = wi >> 3, kc = wi & 7;
        float f = lw[(kc * 64 + lane) * 17 + s];
        ull bits = __ballot(f > 0.f);
        if (lane == 0) out[(size_t)wi * 1024 + co] = bits;
    }
}

// lw2 (1024x1024) / lw3 (10x1024): stored [wi][rows], bit b <-> k = wi*64+b
__global__ __launch_bounds__(256) void pack_lw_lin(const float* __restrict__ w,
                                                   ull* __restrict__ out,
                                                   int rows) {
    __shared__ float lw[1024];
    int co = blockIdx.x;
    const float* base = w + (size_t)co * 1024;
    for (int k = threadIdx.x; k < 1024; k += 256) lw[k] = base[k];
    __syncthreads();
    int lane = threadIdx.x & 63;
    int wv = threadIdx.x >> 6;
    for (int wi = wv; wi < 16; wi += 4) {
        float f = lw[wi * 64 + lane];
        ull bits = __ballot(f > 0.f);
        if (lane == 0) out[(size_t)wi * rows + co] = bits;
    }
}

// ---------------------------------------------------------------------------
// Conv1: real input x (32,3,32,32), binarized weights (384,3,3,3), fp64 acc.
// One block per (n, row): x window staged in LDS, 384 threads = one co each.
// ---------------------------------------------------------------------------
__global__ __launch_bounds__(384) void conv1_bn_sign(
    const float* __restrict__ x, const float* __restrict__ cw,
    const float* __restrict__ cb, const float* __restrict__ g,
    const float* __restrict__ bb, const float* __restrict__ m,
    const float* __restrict__ v, ull* __restrict__ out) {
    __shared__ double xs[3][3][34];
    int blk = blockIdx.x;             // n*32 + y
    int y = blk & 31, n = blk >> 5;
    for (int i = threadIdx.x; i < 3 * 3 * 34; i += 384) {
        int col = i % 34;
        int r = i / 34;
        int ky = r % 3, ci = r / 3;
        int iy = y + ky - 1, ix = col - 1;
        double vv = 0.0;
        if ((unsigned)iy < 32u && (unsigned)ix < 32u)
            vv = (double)x[(((size_t)n * 3 + ci) * 32 + iy) * 32 + ix];
        xs[ci][ky][col] = vv;
    }
    __syncthreads();
    int co = threadIdx.x;
    double ws[27];
#pragma unroll
    for (int q = 0; q < 27; ++q) {
        float wv = cw[(size_t)co * 27 + q];
        ws[q] = (wv > 0.f) ? 1.0 : ((wv < 0.f) ? -1.0 : 0.0);
    }
    double inv = (double)g[co] / sqrt((double)v[co] + EPS);
    double addc = (double)cb[co] - (double)m[co];
    double bbv = (double)bb[co];
    ull* op = out + (size_t)blk * 32 * 6 + (co >> 6);
    for (int xx = 0; xx < 32; ++xx) {
        double acc = 0.0;
#pragma unroll
        for (int ci = 0; ci < 3; ++ci)
#pragma unroll
            for (int ky = 0; ky < 3; ++ky)
#pragma unroll
                for (int kx = 0; kx < 3; ++kx)
                    acc = fma(ws[(ci * 3 + ky) * 3 + kx], xs[ci][ky][xx + kx], acc);
        double tt = (acc + addc) * inv + bbv;
        ull mask = __ballot(tt > 0.0);
        if ((threadIdx.x & 63) == 0) op[(size_t)xx * 6] = mask;
    }
}

// ---------------------------------------------------------------------------
// Binary conv (+fused 2x2 maxpool) + bias + BN threshold + sign-pack.
// kc-MAJOR, NO LDS: outer loop over single 64-channel words. Live set is
// tiny (w[9]=18 VGPR + a[WW]<=20 VGPR + tot[NPIX]) so it fits the RA's
// occupancy target — R3-R5 showed the scheduler refuses >48-reg live
// ranges and rematerializes instead. Activations are read directly from
// global with BLOCK-UNIFORM addresses (1 coalesced 8B request per wave,
// likely scalarized) — no staging loop, no __syncthreads, no LDS-unit
// pressure. Border taps are SKIPPED via uniform row/col guards; the
// dot formula dot = cy*cx*KC*64 - 2*tot already accounts for skipped
// taps (verified in R2-R5). Integer-exact; pool on raw integer dots.
// ---------------------------------------------------------------------------
template <int KC, int POOL, int PB, int BLK, int HIN, int WIN, int COUT>
__global__ __launch_bounds__(BLK, 6) void binconv_kernel(
    const ull* __restrict__ act, const ull* __restrict__ wgt,
    const float* __restrict__ cb, const float* __restrict__ g,
    const float* __restrict__ bb, const float* __restrict__ m,
    const float* __restrict__ v, ull* __restrict__ out) {
    constexpr int HOUT = HIN / POOL, WOUT = WIN / POOL;
    constexpr int WH = POOL + 2, WW = PB * POOL + 2;
    constexpr int NPIX = PB * POOL * POOL;
    constexpr int XB = WOUT / PB;
    int xb = (int)blockIdx.x % XB;
    int t = (int)blockIdx.x / XB;
    int yo = t % HOUT;
    int n = t / HOUT;
    int xo0 = xb * PB;
    int iy0 = yo * POOL - 1, ix0 = xo0 * POOL - 1;
    const bool left = (ix0 >= 0);                // col 0 of window valid
    const bool right = (ix0 + WW <= WIN);        // col WW-1 valid

    int co = blockIdx.y * BLK + (int)threadIdx.x;

    int tot[NPIX];
#pragma unroll
    for (int i = 0; i < NPIX; ++i) tot[i] = 0;

#pragma unroll 1
    for (int ch = 0; ch < KC; ++ch) {
        ull w[9];
#pragma unroll
        for (int tap = 0; tap < 9; ++tap)
            w[tap] = wgt[((size_t)tap * KC + ch) * COUT + co];

#pragma unroll
        for (int r = 0; r < WH; ++r) {
            int iy = iy0 + r;
            if ((unsigned)iy >= (unsigned)HIN) continue;   // uniform skip
            const ull* bp =
                act + (((size_t)n * HIN + iy) * WIN + ix0) * KC + ch;
            ull a[WW];
            a[0] = left ? bp[0] : 0;
#pragma unroll
            for (int c = 1; c < WW - 1; ++c) a[c] = bp[(size_t)c * KC];
            a[WW - 1] = right ? bp[(size_t)(WW - 1) * KC] : 0;

#pragma unroll
            for (int c = 0; c < WW; ++c) {
                if (c == 0 && !left) continue;        // uniform
                if (c == WW - 1 && !right) continue;  // uniform
#pragma unroll
                for (int dy = (r >= 2 ? r - 2 : 0);
                     dy <= (r < POOL - 1 ? r : POOL - 1); ++dy) {
                    const int ky = r - dy;
#pragma unroll
                    for (int j = (c >= 2 ? c - 2 : 0);
                         j <= (c < PB * POOL - 1 ? c : PB * POOL - 1); ++j) {
                        const int kx = c - j;
                        const int tap = ky * 3 + kx;
                        const int pix =
                            (j / POOL) * (POOL * POOL) + dy * POOL + (j % POOL);
                        tot[pix] += __popcll(a[c] ^ w[tap]);
                    }
                }
            }
        }
    }

    double inv = (double)g[co] / sqrt((double)v[co] + EPS);
    double addc = (double)cb[co] - (double)m[co];
    double bbv = (double)bb[co];

    constexpr int KCOUT = COUT >> 6;
#pragma unroll
    for (int px = 0; px < PB; ++px) {
        int best = 0x80000000;
#pragma unroll
        for (int dy = 0; dy < POOL; ++dy)
#pragma unroll
            for (int dx = 0; dx < POOL; ++dx) {
                int py = yo * POOL + dy;
                int pxa = (xo0 + px) * POOL + dx;
                int cy = 3 - (py == 0) - (py == HIN - 1);
                int cx = 3 - (pxa == 0) - (pxa == WIN - 1);
                int dot = cy * cx * (KC * 64) -
                          2 * tot[px * POOL * POOL + dy * POOL + dx];
                best = max(best, dot);
            }
        double tt = ((double)best + addc) * inv + bbv;
        ull mask = __ballot(tt > 0.0);
        if ((threadIdx.x & 63) == 0)
            out[(size_t)((n * HOUT + yo) * WOUT + xo0 + px) * KCOUT + (co >> 6)] =
                mask;
    }
}

// ---------------------------------------------------------------------------
// Binary FC + bias + BN threshold + sign-pack. Grid = (N, Cout/256).
// ---------------------------------------------------------------------------
template <int KCIN>
__global__ __launch_bounds__(256) void binfc_kernel(
    const ull* __restrict__ act, const ull* __restrict__ wgt,
    const float* __restrict__ lb, const float* __restrict__ g,
    const float* __restrict__ bb, const float* __restrict__ m,
    const float* __restrict__ v, ull* __restrict__ out, int Cout) {
    int n = blockIdx.x;
    int co = blockIdx.y * 256 + (int)threadIdx.x;
    const ull* ap = act + (size_t)n * KCIN;
    int mism = 0;
#pragma unroll 8
    for (int kc = 0; kc < KCIN; ++kc)
        mism += __popcll(ap[kc] ^ wgt[(size_t)kc * Cout + co]);
    int dot = 64 * KCIN - 2 * mism;
    double tt = ((double)dot + (double)lb[co] - (double)m[co]) *
                    ((double)g[co] / sqrt((double)v[co] + EPS)) +
                (double)bb[co];
    ull mask = __ballot(tt > 0.0);
    if (((int)threadIdx.x & 63) == 0)
        out[(size_t)n * (Cout >> 6) + ((unsigned)co >> 6)] = mask;
}

// ---------------------------------------------------------------------------
// Final FC3 (1024 -> 10) + affine-free BN + log_softmax, fp64. Grid = N.
// ---------------------------------------------------------------------------
__global__ __launch_bounds__(64) void fc3_softmax(
    const ull* __restrict__ act, const ull* __restrict__ wgt,
    const float* __restrict__ lb, const float* __restrict__ m9,
    const float* __restrict__ v9, float* __restrict__ out) {
    int n = blockIdx.x;
    __shared__ double z[10];
    int j = threadIdx.x;
    if (j < 10) {
        const ull* ap = act + (size_t)n * 16;
        int mism = 0;
#pragma unroll
        for (int kc = 0; kc < 16; ++kc) mism += __popcll(ap[kc] ^ wgt[kc * 10 + j]);
        int dot = 1024 - 2 * mism;
        z[j] = ((double)dot + (double)lb[j] - (double)m9[j]) /
               sqrt((double)v9[j] + EPS);
    }
    __syncthreads();
    if (j < 10) {
        double mx = z[0];
        for (int k = 1; k < 10; ++k) mx = fmax(mx, z[k]);
        double s = 0.0;
        for (int k = 0; k < 10; ++k) s += exp(z[k] - mx);
        out[n * 10 + j] = (float)(z[j] - mx - log(s));
    }
}

// ---------------------------------------------------------------------------
extern "C" void kernel_launch(void* const* d_in, const int* in_sizes, int n_in,
                              void* d_out, int out_size, void* d_ws, size_t ws_size,
                              hipStream_t stream) {
    (void)in_sizes; (void)n_in; (void)out_size; (void)ws_size;

    const float* x   = (const float*)d_in[0];
    const float* cw[6], *cbv[6];
    for (int i = 0; i < 6; ++i) {
        cw[i]  = (const float*)d_in[1 + 2 * i];
        cbv[i] = (const float*)d_in[2 + 2 * i];
    }
    const float *G[8], *B[8], *M[8], *V[8];
    for (int i = 0; i < 8; ++i) {
        G[i] = (const float*)d_in[13 + 4 * i];
        B[i] = (const float*)d_in[14 + 4 * i];
        M[i] = (const float*)d_in[15 + 4 * i];
        V[i] = (const float*)d_in[16 + 4 * i];
    }
    const float* m9  = (const float*)d_in[45];
    const float* v9  = (const float*)d_in[46];
    const float* lw1 = (const float*)d_in[47];
    const float* lb1 = (const float*)d_in[48];
    const float* lw2 = (const float*)d_in[49];
    const float* lb2 = (const float*)d_in[50];
    const float* lw3 = (const float*)d_in[51];
    const float* lb3 = (const float*)d_in[52];
    float* outp = (float*)d_out;

    ull* ws = (ull*)d_ws;
    // word offsets (8B units)
    ull* W2  = ws + 0;        // 20736
    ull* W3  = ws + 20736;    // 41472
    ull* W4  = ws + 62208;    // 82944
    ull* W5  = ws + 145152;   // 165888
    ull* W6  = ws + 311040;   // 110592
    ull* FW1 = ws + 421632;   // 131072
    ull* FW2 = ws + 552704;   // 16384
    ull* FW3 = ws + 569088;   // 160
    ull* A1  = ws + 569248;   // 196608 : 32x32x32 pixels x 6 words
    ull* A2  = ws + 765856;   // 49152  : 32x16x16 x 6
    ull* A3  = ws + 815008;   // 98304  : 32x16x16 x 12
    ull* A4  = ws + 913312;   // 24576  : 32x8x8 x 12
    ull* A5  = ws + 937888;   // 49152  : 32x8x8 x 24
    ull* A6  = ws + 987040;   // 4096   : 32x4x4 x 8
    ull* F1  = ws + 991136;   // 512    : 32 x 16
    ull* F2  = ws + 991648;   // 512    : 32 x 16

    // ---- pack weights (ballot-style, coalesced staging) ----
    pack_conv_w<<<384, 256, 384 * 9 * 4, stream>>>(cw[1], W2, 384, 384);
    pack_conv_w<<<768, 256, 384 * 9 * 4, stream>>>(cw[2], W3, 768, 384);
    pack_conv_w<<<768, 256, 768 * 9 * 4, stream>>>(cw[3], W4, 768, 768);
    pack_conv_w<<<1536, 256, 768 * 9 * 4, stream>>>(cw[4], W5, 1536, 768);
    pack_conv_w<<<512, 256, 1536 * 9 * 4, stream>>>(cw[5], W6, 512, 1536);
    pack_lw1<<<1024, 256, 0, stream>>>(lw1, FW1);
    pack_lw_lin<<<1024, 256, 0, stream>>>(lw2, FW2, 1024);
    pack_lw_lin<<<10, 256, 0, stream>>>(lw3, FW3, 10);

    // ---- layer 1: real conv, fp64, LDS-staged ----
    conv1_bn_sign<<<32 * 32, 384, 0, stream>>>(x, cw[0], cbv[0], G[0], B[0],
                                               M[0], V[0], A1);
    // ---- binary conv stack (kc-major, LDS-free) ----
    binconv_kernel<6, 2, 4, 192, 32, 32, 384><<<dim3(2048, 2), 192, 0, stream>>>(
        A1, W2, cbv[1], G[1], B[1], M[1], V[1], A2);
    binconv_kernel<6, 1, 8, 256, 16, 16, 768><<<dim3(1024, 3), 256, 0, stream>>>(
        A2, W3, cbv[2], G[2], B[2], M[2], V[2], A3);
    binconv_kernel<12, 2, 4, 256, 16, 16, 768><<<dim3(512, 3), 256, 0, stream>>>(
        A3, W4, cbv[3], G[3], B[3], M[3], V[3], A4);
    binconv_kernel<12, 1, 8, 256, 8, 8, 1536><<<dim3(256, 6), 256, 0, stream>>>(
        A4, W5, cbv[4], G[4], B[4], M[4], V[4], A5);
    binconv_kernel<24, 2, 4, 256, 8, 8, 512><<<dim3(128, 2), 256, 0, stream>>>(
        A5, W6, cbv[5], G[5], B[5], M[5], V[5], A6);
    // ---- FC stack ----
    binfc_kernel<128><<<dim3(32, 4), 256, 0, stream>>>(A6, FW1, lb1, G[6], B[6],
                                                       M[6], V[6], F1, 1024);
    binfc_kernel<16><<<dim3(32, 4), 256, 0, stream>>>(F1, FW2, lb2, G[7], B[7],
                                                      M[7], V[7], F2, 1024);
    fc3_softmax<<<32, 64, 0, stream>>>(F2, FW3, lb3, m9, v9, outp);
}